// Round 13
// baseline (311.678 us; speedup 1.0000x reference)
//
#include <hip/hip_runtime.h>

#define NT 256
#define NBC 49         // coarse buckets (2048 nodes each), ceil(100000/2048)
#define CAPC 69632     // slots per coarse bucket (mean 65536, +16 sigma)
#define EPBC 8192      // edges per block, coarse pass
#define CAP 16384      // slots per fine bucket (256 nodes; mean 8192)
#define MAXF 512       // fine bucket count upper bound (391 actual)

typedef __bf16 bf16x8 __attribute__((ext_vector_type(8)));
typedef float f32x4 __attribute__((ext_vector_type(4)));

__device__ __forceinline__ unsigned short f2bf(float f) {
    unsigned int u = __float_as_uint(f);
    unsigned int r = u + 0x7FFFu + ((u >> 16) & 1u);   // RNE
    return (unsigned short)(r >> 16);
}
__device__ __forceinline__ float bf2f(unsigned short h) {
    return __uint_as_float(((unsigned int)h) << 16);
}

// ---------------------------------------------------------------------------
// Init: block 0 inits all cursors; blocks 1..16 convert W1 -> W1T hi/lo
// ---------------------------------------------------------------------------
__global__ __launch_bounds__(512) void init_all(int* __restrict__ gcurCD,
                                                int* __restrict__ gcurCS,
                                                int* __restrict__ gcurF,
                                                const float* __restrict__ W1,
                                                unsigned short* __restrict__ w1t_hi,
                                                unsigned short* __restrict__ w1t_lo, int nbf) {
    if (blockIdx.x == 0) {
        int i = threadIdx.x;
        if (i < NBC) { gcurCD[i] = i * CAPC; gcurCS[i] = i * CAPC; }
        if (i < nbf) gcurF[i] = i * CAP;
    } else {
        int t = (blockIdx.x - 1) * 512 + threadIdx.x;
        if (t < 512 * 16) {
            int k = t >> 4, c = t & 15;
            float f = W1[k * 16 + c];
            unsigned short h = f2bf(f);
            w1t_hi[c * 512 + k] = h;
            w1t_lo[c * 512 + k] = f2bf(f - bf2f(h));
        }
    }
}

// ---------------------------------------------------------------------------
// Coarse scatter: 49 buckets -> runs of ~167 edges per (block,bucket).
//   ebinCD[slot] = src | (dst&2047)<<17   (28 bits)
//   ebinCS[slot] = (u16)(src & 2047)
// ---------------------------------------------------------------------------
__global__ __launch_bounds__(NT) void coarse_scatter(const int* __restrict__ src,
                                                     const int* __restrict__ dst,
                                                     int* __restrict__ gcurCD,
                                                     int* __restrict__ gcurCS,
                                                     unsigned int* __restrict__ ebinCD,
                                                     unsigned short* __restrict__ ebinCS,
                                                     int e) {
    __shared__ int hD[NBC], hS[NBC], cD[NBC], cS[NBC];
    int tid = threadIdx.x;
    if (tid < NBC) { hD[tid] = 0; hS[tid] = 0; }
    __syncthreads();
    int p0 = blockIdx.x * EPBC;
    int pend = min(p0 + EPBC, e);
    for (int p = p0 + tid; p < pend; p += NT) {
        atomicAdd(&hD[dst[p] >> 11], 1);
        atomicAdd(&hS[src[p] >> 11], 1);
    }
    __syncthreads();
    if (tid < NBC) {
        cD[tid] = hD[tid] ? atomicAdd(&gcurCD[tid], hD[tid]) : 0;
        cS[tid] = hS[tid] ? atomicAdd(&gcurCS[tid], hS[tid]) : 0;
    }
    __syncthreads();
    for (int p = p0 + tid; p < pend; p += NT) {
        int s = src[p], d = dst[p];
        int c = d >> 11;
        int slot = atomicAdd(&cD[c], 1);
        if (slot < (c + 1) * CAPC)
            ebinCD[slot] = (unsigned int)s | ((unsigned int)(d & 2047) << 17);
        int cs = s >> 11;
        int slot2 = atomicAdd(&cS[cs], 1);
        if (slot2 < (cs + 1) * CAPC)
            ebinCS[slot2] = (unsigned short)(s & 2047);
    }
}

// ---------------------------------------------------------------------------
// Fused: blocks [0, NBC*8) = fine D-scatter; blocks [NBC*8, NBC*16) = S-hist
// ---------------------------------------------------------------------------
__global__ __launch_bounds__(NT) void fine_plus_shist(const unsigned int* __restrict__ ebinCD,
                                                      const int* __restrict__ gcurCD,
                                                      int* __restrict__ gcurF,
                                                      unsigned int* __restrict__ ebinD,
                                                      const unsigned short* __restrict__ ebinCS,
                                                      const int* __restrict__ gcurCS,
                                                      int* __restrict__ cntS, int n) {
    int tid = threadIdx.x;
    if (blockIdx.x < NBC * 8) {
        __shared__ int hF[8], cF[8];
        int c = blockIdx.x >> 3, k = blockIdx.x & 7;
        if (tid < 8) hF[tid] = 0;
        __syncthreads();
        int p0c = c * CAPC;
        int p1 = gcurCD[c];
        int len = p1 - p0c;
        int chunk = (len + 7) >> 3;
        int q0 = p0c + k * chunk;
        int q1 = min(q0 + chunk, p1);
        for (int p = q0 + tid; p < q1; p += NT)
            atomicAdd(&hF[(ebinCD[p] >> 25) & 7], 1);
        __syncthreads();
        if (tid < 8) {
            int h = hF[tid];
            cF[tid] = h ? atomicAdd(&gcurF[c * 8 + tid], h) : 0;
        }
        __syncthreads();
        for (int p = q0 + tid; p < q1; p += NT) {
            unsigned int w = ebinCD[p];
            int f = (w >> 25) & 7;
            int slot = atomicAdd(&cF[f], 1);
            if (slot < (c * 8 + f + 1) * CAP)
                ebinD[slot] = (w & 0x1FFFFu) | (((w >> 17) & 255u) << 17);
        }
    } else {
        __shared__ int cnt[2048];
        int bb = blockIdx.x - NBC * 8;
        int c = bb >> 3, k = bb & 7;
        for (int i = tid; i < 2048; i += NT) cnt[i] = 0;
        __syncthreads();
        int p0c = c * CAPC;
        int p1 = gcurCS[c];
        int len = p1 - p0c;
        int chunk = (len + 7) >> 3;
        int q0 = p0c + k * chunk;
        int q1 = min(q0 + chunk, p1);
        for (int p = q0 + tid; p < q1; p += NT)
            atomicAdd(&cnt[ebinCS[p]], 1);
        __syncthreads();
        int node0 = c * 2048;
        for (int i = tid; i < 2048; i += NT) {
            int v = cnt[i];
            if (v && node0 + i < n) atomicAdd(&cntS[node0 + i], v);
        }
    }
}

// ---------------------------------------------------------------------------
// GEMM1 via split-precision bf16 MFMA (LDS-staged, coalesced):
//   y1bf[i][j] = bf16( (x[i] @ W1)[j] * rsqrt(outdeg[i]) )
// ---------------------------------------------------------------------------
#define GR 64
__global__ __launch_bounds__(NT) void gemm1_mfma(const float* __restrict__ x,
                                                 const unsigned short* __restrict__ w1t_hi,
                                                 const unsigned short* __restrict__ w1t_lo,
                                                 const int* __restrict__ cntS,
                                                 unsigned short* __restrict__ y1bf, int n) {
    __shared__ __attribute__((aligned(16))) unsigned short sh_hi[GR][72];
    __shared__ __attribute__((aligned(16))) unsigned short sh_lo[GR][72];
    int tid = threadIdx.x;
    int w = tid >> 6, l = tid & 63;
    int row0 = blockIdx.x * GR;

    f32x4 acc = {0.f, 0.f, 0.f, 0.f};
    int col = l & 15;
    int kq = (l >> 4) * 8;
    int arow = w * 16 + (l & 15);

    for (int kc = 0; kc < 512; kc += 64) {
        __syncthreads();
#pragma unroll
        for (int i = 0; i < 4; i++) {
            int idx = tid + i * NT;
            int r = idx >> 4;
            int c4 = idx & 15;
            int grow = row0 + r;
            float4 v = make_float4(0.f, 0.f, 0.f, 0.f);
            if (grow < n) v = *(const float4*)&x[(size_t)grow * 512 + kc + c4 * 4];
            ushort4 hv, lv;
            hv.x = f2bf(v.x); lv.x = f2bf(v.x - bf2f(hv.x));
            hv.y = f2bf(v.y); lv.y = f2bf(v.y - bf2f(hv.y));
            hv.z = f2bf(v.z); lv.z = f2bf(v.z - bf2f(hv.z));
            hv.w = f2bf(v.w); lv.w = f2bf(v.w - bf2f(hv.w));
            *(ushort4*)&sh_hi[r][c4 * 4] = hv;
            *(ushort4*)&sh_lo[r][c4 * 4] = lv;
        }
        __syncthreads();
#pragma unroll
        for (int ks = 0; ks < 2; ks++) {
            int klocal = ks * 32 + kq;
            bf16x8 a_hi = *(const bf16x8*)&sh_hi[arow][klocal];
            bf16x8 a_lo = *(const bf16x8*)&sh_lo[arow][klocal];
            int kglob = kc + klocal;
            bf16x8 b_hi = *(const bf16x8*)&w1t_hi[col * 512 + kglob];
            bf16x8 b_lo = *(const bf16x8*)&w1t_lo[col * 512 + kglob];
            acc = __builtin_amdgcn_mfma_f32_16x16x32_bf16(a_hi, b_hi, acc, 0, 0, 0);
            acc = __builtin_amdgcn_mfma_f32_16x16x32_bf16(a_lo, b_hi, acc, 0, 0, 0);
            acc = __builtin_amdgcn_mfma_f32_16x16x32_bf16(a_hi, b_lo, acc, 0, 0, 0);
        }
    }

    int rbase = (l >> 4) * 4;       // D row = (lane>>4)*4 + reg, col = l&15
#pragma unroll
    for (int reg = 0; reg < 4; reg++) {
        int grow = row0 + w * 16 + rbase + reg;
        if (grow < n) {
            float ns = rsqrtf((float)max(cntS[grow], 1));
            y1bf[(size_t)grow * 16 + col] = f2bf(acc[reg] * ns);
        }
    }
}

// ---------------------------------------------------------------------------
// Per-fine-bucket in-degree histogram + LDS scan -> rowoff/rowend, norm_dst,
// then fill esrc (bucket-strided CSR)
// ---------------------------------------------------------------------------
__global__ __launch_bounds__(NT) void dst_fill(const unsigned int* __restrict__ ebinD,
                                               const int* __restrict__ gcurF,
                                               int* __restrict__ rowoff,
                                               int* __restrict__ rowend,
                                               float* __restrict__ norm_dst,
                                               int* __restrict__ esrc, int n) {
    __shared__ int cnt[256], cur[256], tmp[256];
    int b = blockIdx.x, tid = threadIdx.x;
    cnt[tid] = 0;
    __syncthreads();
    int p0 = b * CAP, p1 = gcurF[b];
    for (int p = p0 + tid; p < p1; p += NT) atomicAdd(&cnt[ebinD[p] >> 17], 1);
    __syncthreads();
    int v = cnt[tid];
    int val = v;
    tmp[tid] = val;
    __syncthreads();
    for (int off = 1; off < 256; off <<= 1) {
        int a = (tid >= off) ? tmp[tid - off] : 0;
        __syncthreads();
        val += a;
        tmp[tid] = val;
        __syncthreads();
    }
    int excl = val - v;
    int node = (b << 8) + tid;
    if (node < n) {
        rowoff[node] = p0 + excl;
        rowend[node] = p0 + excl + v;
        norm_dst[node] = rsqrtf((float)max(v, 1));
    }
    cur[tid] = p0 + excl;
    __syncthreads();
    for (int p = p0 + tid; p < p1; p += NT) {
        unsigned int w = ebinD[p];
        int pos = atomicAdd(&cur[w >> 17], 1);
        esrc[pos] = (int)(w & 0x1FFFFu);
    }
}

// ---------------------------------------------------------------------------
// Aggregate layer 1: ONE WAVE PER NODE (4 edges x 16 feats per iter, 2-deep)
//   h1s[d][j] = bf16( relu(sum*nd + b1[j]) * rsqrt(outdeg[d]) )
// ---------------------------------------------------------------------------
__global__ __launch_bounds__(NT) void aggregate_act(const unsigned short* __restrict__ feat,
                                                    const int* __restrict__ rowoff,
                                                    const int* __restrict__ rowend,
                                                    const int* __restrict__ esrc,
                                                    const float* __restrict__ norm_dst,
                                                    const int* __restrict__ cntS,
                                                    const float* __restrict__ b1,
                                                    unsigned short* __restrict__ h1s, int n) {
    int d = blockIdx.x * 4 + (threadIdx.x >> 6);
    if (d >= n) return;
    int l = threadIdx.x & 63;
    int g = l >> 4, j = l & 15;
    int p0 = rowoff[d], p1 = rowend[d];
    float acc = 0.f;
    for (int p = p0; p < p1; p += 8) {
        int pe0 = p + g, pe1 = p + 4 + g;
        float v0 = 0.f, v1 = 0.f;
        if (pe0 < p1) v0 = bf2f(feat[(size_t)esrc[pe0] * 16 + j]);
        if (pe1 < p1) v1 = bf2f(feat[(size_t)esrc[pe1] * 16 + j]);
        acc += v0 + v1;
    }
    acc += __shfl_xor(acc, 16);
    acc += __shfl_xor(acc, 32);
    if (l < 16) {
        float ns = rsqrtf((float)max(cntS[d], 1));
        float v = fmaxf(acc * norm_dst[d] + b1[j], 0.f) * ns;
        h1s[(size_t)d * 16 + j] = f2bf(v);
    }
}

// ---------------------------------------------------------------------------
// Aggregate layer 2: ONE WAVE PER NODE + fused final GEMM
//   out[d][:] = (sum @ W2) * nd + b2   (lane l -> output col l)
// ---------------------------------------------------------------------------
__global__ __launch_bounds__(NT) void aggregate_final(const unsigned short* __restrict__ feat,
                                                      const int* __restrict__ rowoff,
                                                      const int* __restrict__ rowend,
                                                      const int* __restrict__ esrc,
                                                      const float* __restrict__ norm_dst,
                                                      const float* __restrict__ W2,
                                                      const float* __restrict__ b2,
                                                      float* __restrict__ out, int n) {
    __shared__ float sW[16 * 64];
    int tid = threadIdx.x;
    *(float4*)&sW[tid * 4] = *(const float4*)&W2[tid * 4];
    __syncthreads();
    int d = blockIdx.x * 4 + (tid >> 6);
    if (d >= n) return;
    int l = tid & 63;
    int g = l >> 4, j = l & 15;
    int p0 = rowoff[d], p1 = rowend[d];
    float acc = 0.f;
    for (int p = p0; p < p1; p += 8) {
        int pe0 = p + g, pe1 = p + 4 + g;
        float v0 = 0.f, v1 = 0.f;
        if (pe0 < p1) v0 = bf2f(feat[(size_t)esrc[pe0] * 16 + j]);
        if (pe1 < p1) v1 = bf2f(feat[(size_t)esrc[pe1] * 16 + j]);
        acc += v0 + v1;
    }
    acc += __shfl_xor(acc, 16);
    acc += __shfl_xor(acc, 32);
    // every lane now holds the full sum for feature j = l&15
    float nd = norm_dst[d];
    float o = 0.f;
#pragma unroll
    for (int k = 0; k < 16; k++) {
        float ak = __shfl(acc, k, 16);
        o += ak * sW[k * 64 + l];
    }
    out[(size_t)d * 64 + l] = o * nd + b2[l];
}

// ---------------------------------------------------------------------------
// Launch
// ---------------------------------------------------------------------------
extern "C" void kernel_launch(void* const* d_in, const int* in_sizes, int n_in,
                              void* d_out, int out_size, void* d_ws, size_t ws_size,
                              hipStream_t stream) {
    const float* x  = (const float*)d_in[0];
    const float* W1 = (const float*)d_in[1];
    const float* b1 = (const float*)d_in[2];
    const float* W2 = (const float*)d_in[3];
    const float* b2 = (const float*)d_in[4];
    const int* src  = (const int*)d_in[5];
    const int* dst  = (const int*)d_in[6];

    int n = in_sizes[0] / 512;   // 100000
    int e = in_sizes[5];         // 3200000
    float* out = (float*)d_out;

    int nbf = (n + 255) >> 8;    // 391 fine buckets

    char* ws = (char*)d_ws;
    size_t off = 0;
    auto alloc = [&](size_t bytes) { size_t o = off; off = (off + bytes + 255) & ~(size_t)255; return o; };
    int*   cntS   = (int*)(ws + alloc((size_t)n * 4));   // zeroed by memset
    size_t zero_end = off;
    int*   gcurCD = (int*)(ws + alloc(NBC * 4));
    int*   gcurCS = (int*)(ws + alloc(NBC * 4));
    int*   gcurF  = (int*)(ws + alloc(MAXF * 4));
    float* norm_dst = (float*)(ws + alloc((size_t)n * 4));
    int*   rowoff   = (int*)(ws + alloc((size_t)n * 4));
    int*   rowend   = (int*)(ws + alloc((size_t)n * 4));
    unsigned int*   ebinCD = (unsigned int*)(ws + alloc((size_t)NBC * CAPC * 4));
    unsigned short* ebinCS = (unsigned short*)(ws + alloc((size_t)NBC * CAPC * 2));
    unsigned int*   ebinD  = (unsigned int*)(ws + alloc((size_t)nbf * CAP * 4));
    int*   esrc  = (int*)(ws + alloc((size_t)nbf * CAP * 4));
    unsigned short* y1bf = (unsigned short*)(ws + alloc((size_t)n * 16 * 2));
    unsigned short* h1s  = (unsigned short*)(ws + alloc((size_t)n * 16 * 2));
    unsigned short* w1t_hi = (unsigned short*)(ws + alloc(16 * 512 * 2));
    unsigned short* w1t_lo = (unsigned short*)(ws + alloc(16 * 512 * 2));
    if (off > ws_size) return;

    int cbb = (e + EPBC - 1) / EPBC;      // 391
    int fsb = NBC * 16;                   // 784 (fine + s_hist halves)
    int grb = (n + GR - 1) / GR;          // 1563
    int agb = (n + 3) / 4;                // 25000 (4 waves/block, 1 node/wave)

    hipMemsetAsync(cntS, 0, zero_end, stream);

    init_all       <<<17, 512, 0, stream>>>(gcurCD, gcurCS, gcurF, W1, w1t_hi, w1t_lo, nbf);
    coarse_scatter <<<cbb, NT, 0, stream>>>(src, dst, gcurCD, gcurCS, ebinCD, ebinCS, e);
    fine_plus_shist<<<fsb, NT, 0, stream>>>(ebinCD, gcurCD, gcurF, ebinD, ebinCS, gcurCS, cntS, n);
    gemm1_mfma     <<<grb, NT, 0, stream>>>(x, w1t_hi, w1t_lo, cntS, y1bf, n);
    dst_fill       <<<nbf, NT, 0, stream>>>(ebinD, gcurF, rowoff, rowend, norm_dst, esrc, n);
    aggregate_act  <<<agb, NT, 0, stream>>>(y1bf, rowoff, rowend, esrc, norm_dst, cntS, b1, h1s, n);
    aggregate_final<<<agb, NT, 0, stream>>>(h1s, rowoff, rowend, esrc, norm_dst, W2, b2, out, n);
}

// Round 14
// 229.819 us; speedup vs baseline: 1.3562x; 1.3562x over previous
//
#include <hip/hip_runtime.h>

#define NT 256
#define NBC 49         // coarse buckets (2048 nodes each), ceil(100000/2048)
#define CAPC 69632     // slots per coarse bucket (mean 65536, +16 sigma)
#define EPBC 8192      // edges per block, coarse pass
#define CAP 16384      // slots per fine bucket (256 nodes; mean 8192)
#define MAXF 512       // fine bucket count upper bound (391 actual)

typedef __bf16 bf16x8 __attribute__((ext_vector_type(8)));
typedef float f32x4 __attribute__((ext_vector_type(4)));

__device__ __forceinline__ unsigned short f2bf(float f) {
    unsigned int u = __float_as_uint(f);
    unsigned int r = u + 0x7FFFu + ((u >> 16) & 1u);   // RNE
    return (unsigned short)(r >> 16);
}
__device__ __forceinline__ float bf2f(unsigned short h) {
    return __uint_as_float(((unsigned int)h) << 16);
}

// ---------------------------------------------------------------------------
// Init: block 0 inits all cursors; blocks 1..16 convert W1 -> W1T hi/lo
// ---------------------------------------------------------------------------
__global__ __launch_bounds__(512) void init_all(int* __restrict__ gcurCD,
                                                int* __restrict__ gcurCS,
                                                int* __restrict__ gcurF,
                                                const float* __restrict__ W1,
                                                unsigned short* __restrict__ w1t_hi,
                                                unsigned short* __restrict__ w1t_lo, int nbf) {
    if (blockIdx.x == 0) {
        int i = threadIdx.x;
        if (i < NBC) { gcurCD[i] = i * CAPC; gcurCS[i] = i * CAPC; }
        if (i < nbf) gcurF[i] = i * CAP;
    } else {
        int t = (blockIdx.x - 1) * 512 + threadIdx.x;
        if (t < 512 * 16) {
            int k = t >> 4, c = t & 15;
            float f = W1[k * 16 + c];
            unsigned short h = f2bf(f);
            w1t_hi[c * 512 + k] = h;
            w1t_lo[c * 512 + k] = f2bf(f - bf2f(h));
        }
    }
}

// ---------------------------------------------------------------------------
// Coarse scatter: 49 buckets -> runs of ~167 edges per (block,bucket).
//   ebinCD[slot] = src | (dst&2047)<<17   (28 bits)
//   ebinCS[slot] = (u16)(src & 2047)
// ---------------------------------------------------------------------------
__global__ __launch_bounds__(NT) void coarse_scatter(const int* __restrict__ src,
                                                     const int* __restrict__ dst,
                                                     int* __restrict__ gcurCD,
                                                     int* __restrict__ gcurCS,
                                                     unsigned int* __restrict__ ebinCD,
                                                     unsigned short* __restrict__ ebinCS,
                                                     int e) {
    __shared__ int hD[NBC], hS[NBC], cD[NBC], cS[NBC];
    int tid = threadIdx.x;
    if (tid < NBC) { hD[tid] = 0; hS[tid] = 0; }
    __syncthreads();
    int p0 = blockIdx.x * EPBC;
    int pend = min(p0 + EPBC, e);
    for (int p = p0 + tid; p < pend; p += NT) {
        atomicAdd(&hD[dst[p] >> 11], 1);
        atomicAdd(&hS[src[p] >> 11], 1);
    }
    __syncthreads();
    if (tid < NBC) {
        cD[tid] = hD[tid] ? atomicAdd(&gcurCD[tid], hD[tid]) : 0;
        cS[tid] = hS[tid] ? atomicAdd(&gcurCS[tid], hS[tid]) : 0;
    }
    __syncthreads();
    for (int p = p0 + tid; p < pend; p += NT) {
        int s = src[p], d = dst[p];
        int c = d >> 11;
        int slot = atomicAdd(&cD[c], 1);
        if (slot < (c + 1) * CAPC)
            ebinCD[slot] = (unsigned int)s | ((unsigned int)(d & 2047) << 17);
        int cs = s >> 11;
        int slot2 = atomicAdd(&cS[cs], 1);
        if (slot2 < (cs + 1) * CAPC)
            ebinCS[slot2] = (unsigned short)(s & 2047);
    }
}

// ---------------------------------------------------------------------------
// Fused: blocks [0, NBC*8) = fine D-scatter; blocks [NBC*8, NBC*16) = S-hist
// ---------------------------------------------------------------------------
__global__ __launch_bounds__(NT) void fine_plus_shist(const unsigned int* __restrict__ ebinCD,
                                                      const int* __restrict__ gcurCD,
                                                      int* __restrict__ gcurF,
                                                      unsigned int* __restrict__ ebinD,
                                                      const unsigned short* __restrict__ ebinCS,
                                                      const int* __restrict__ gcurCS,
                                                      int* __restrict__ cntS, int n) {
    int tid = threadIdx.x;
    if (blockIdx.x < NBC * 8) {
        __shared__ int hF[8], cF[8];
        int c = blockIdx.x >> 3, k = blockIdx.x & 7;
        if (tid < 8) hF[tid] = 0;
        __syncthreads();
        int p0c = c * CAPC;
        int p1 = gcurCD[c];
        int len = p1 - p0c;
        int chunk = (len + 7) >> 3;
        int q0 = p0c + k * chunk;
        int q1 = min(q0 + chunk, p1);
        for (int p = q0 + tid; p < q1; p += NT)
            atomicAdd(&hF[(ebinCD[p] >> 25) & 7], 1);
        __syncthreads();
        if (tid < 8) {
            int h = hF[tid];
            cF[tid] = h ? atomicAdd(&gcurF[c * 8 + tid], h) : 0;
        }
        __syncthreads();
        for (int p = q0 + tid; p < q1; p += NT) {
            unsigned int w = ebinCD[p];
            int f = (w >> 25) & 7;
            int slot = atomicAdd(&cF[f], 1);
            if (slot < (c * 8 + f + 1) * CAP)
                ebinD[slot] = (w & 0x1FFFFu) | (((w >> 17) & 255u) << 17);
        }
    } else {
        __shared__ int cnt[2048];
        int bb = blockIdx.x - NBC * 8;
        int c = bb >> 3, k = bb & 7;
        for (int i = tid; i < 2048; i += NT) cnt[i] = 0;
        __syncthreads();
        int p0c = c * CAPC;
        int p1 = gcurCS[c];
        int len = p1 - p0c;
        int chunk = (len + 7) >> 3;
        int q0 = p0c + k * chunk;
        int q1 = min(q0 + chunk, p1);
        for (int p = q0 + tid; p < q1; p += NT)
            atomicAdd(&cnt[ebinCS[p]], 1);
        __syncthreads();
        int node0 = c * 2048;
        for (int i = tid; i < 2048; i += NT) {
            int v = cnt[i];
            if (v && node0 + i < n) atomicAdd(&cntS[node0 + i], v);
        }
    }
}

// ---------------------------------------------------------------------------
// GEMM1 via split-precision bf16 MFMA (LDS-staged, coalesced):
//   y1bf[i][j] = bf16( (x[i] @ W1)[j] * rsqrt(outdeg[i]) )
// ---------------------------------------------------------------------------
#define GR 64
__global__ __launch_bounds__(NT) void gemm1_mfma(const float* __restrict__ x,
                                                 const unsigned short* __restrict__ w1t_hi,
                                                 const unsigned short* __restrict__ w1t_lo,
                                                 const int* __restrict__ cntS,
                                                 unsigned short* __restrict__ y1bf, int n) {
    __shared__ __attribute__((aligned(16))) unsigned short sh_hi[GR][72];
    __shared__ __attribute__((aligned(16))) unsigned short sh_lo[GR][72];
    int tid = threadIdx.x;
    int w = tid >> 6, l = tid & 63;
    int row0 = blockIdx.x * GR;

    f32x4 acc = {0.f, 0.f, 0.f, 0.f};
    int col = l & 15;
    int kq = (l >> 4) * 8;
    int arow = w * 16 + (l & 15);

    for (int kc = 0; kc < 512; kc += 64) {
        __syncthreads();
#pragma unroll
        for (int i = 0; i < 4; i++) {
            int idx = tid + i * NT;
            int r = idx >> 4;
            int c4 = idx & 15;
            int grow = row0 + r;
            float4 v = make_float4(0.f, 0.f, 0.f, 0.f);
            if (grow < n) v = *(const float4*)&x[(size_t)grow * 512 + kc + c4 * 4];
            ushort4 hv, lv;
            hv.x = f2bf(v.x); lv.x = f2bf(v.x - bf2f(hv.x));
            hv.y = f2bf(v.y); lv.y = f2bf(v.y - bf2f(hv.y));
            hv.z = f2bf(v.z); lv.z = f2bf(v.z - bf2f(hv.z));
            hv.w = f2bf(v.w); lv.w = f2bf(v.w - bf2f(hv.w));
            *(ushort4*)&sh_hi[r][c4 * 4] = hv;
            *(ushort4*)&sh_lo[r][c4 * 4] = lv;
        }
        __syncthreads();
#pragma unroll
        for (int ks = 0; ks < 2; ks++) {
            int klocal = ks * 32 + kq;
            bf16x8 a_hi = *(const bf16x8*)&sh_hi[arow][klocal];
            bf16x8 a_lo = *(const bf16x8*)&sh_lo[arow][klocal];
            int kglob = kc + klocal;
            bf16x8 b_hi = *(const bf16x8*)&w1t_hi[col * 512 + kglob];
            bf16x8 b_lo = *(const bf16x8*)&w1t_lo[col * 512 + kglob];
            acc = __builtin_amdgcn_mfma_f32_16x16x32_bf16(a_hi, b_hi, acc, 0, 0, 0);
            acc = __builtin_amdgcn_mfma_f32_16x16x32_bf16(a_lo, b_hi, acc, 0, 0, 0);
            acc = __builtin_amdgcn_mfma_f32_16x16x32_bf16(a_hi, b_lo, acc, 0, 0, 0);
        }
    }

    int rbase = (l >> 4) * 4;       // D row = (lane>>4)*4 + reg, col = l&15
#pragma unroll
    for (int reg = 0; reg < 4; reg++) {
        int grow = row0 + w * 16 + rbase + reg;
        if (grow < n) {
            float ns = rsqrtf((float)max(cntS[grow], 1));
            y1bf[(size_t)grow * 16 + col] = f2bf(acc[reg] * ns);
        }
    }
}

// ---------------------------------------------------------------------------
// Per-fine-bucket in-degree histogram + LDS scan -> rowoff/rowend, norm_dst,
// then fill esrc (bucket-strided CSR)
// ---------------------------------------------------------------------------
__global__ __launch_bounds__(NT) void dst_fill(const unsigned int* __restrict__ ebinD,
                                               const int* __restrict__ gcurF,
                                               int* __restrict__ rowoff,
                                               int* __restrict__ rowend,
                                               float* __restrict__ norm_dst,
                                               int* __restrict__ esrc, int n) {
    __shared__ int cnt[256], cur[256], tmp[256];
    int b = blockIdx.x, tid = threadIdx.x;
    cnt[tid] = 0;
    __syncthreads();
    int p0 = b * CAP, p1 = gcurF[b];
    for (int p = p0 + tid; p < p1; p += NT) atomicAdd(&cnt[ebinD[p] >> 17], 1);
    __syncthreads();
    int v = cnt[tid];
    int val = v;
    tmp[tid] = val;
    __syncthreads();
    for (int off = 1; off < 256; off <<= 1) {
        int a = (tid >= off) ? tmp[tid - off] : 0;
        __syncthreads();
        val += a;
        tmp[tid] = val;
        __syncthreads();
    }
    int excl = val - v;
    int node = (b << 8) + tid;
    if (node < n) {
        rowoff[node] = p0 + excl;
        rowend[node] = p0 + excl + v;
        norm_dst[node] = rsqrtf((float)max(v, 1));
    }
    cur[tid] = p0 + excl;
    __syncthreads();
    for (int p = p0 + tid; p < p1; p += NT) {
        unsigned int w = ebinD[p];
        int pos = atomicAdd(&cur[w >> 17], 1);
        esrc[pos] = (int)(w & 0x1FFFFu);
    }
}

// ---------------------------------------------------------------------------
// Aggregate layer 1 (CSR, 16 lanes/node, 8-deep gather pipeline) + fused act:
//   h1s[d][j] = bf16( relu(sum*nd + b1[j]) * rsqrt(outdeg[d]) )
// ---------------------------------------------------------------------------
__global__ __launch_bounds__(NT) void aggregate_act(const unsigned short* __restrict__ feat,
                                                    const int* __restrict__ rowoff,
                                                    const int* __restrict__ rowend,
                                                    const int* __restrict__ esrc,
                                                    const float* __restrict__ norm_dst,
                                                    const int* __restrict__ cntS,
                                                    const float* __restrict__ b1,
                                                    unsigned short* __restrict__ h1s, int n) {
    int tid = threadIdx.x;
    int d = blockIdx.x * 16 + (tid >> 4);
    int j = tid & 15;
    if (d >= n) return;
    int p = rowoff[d], end = rowend[d];
    float a0 = 0.f, a1 = 0.f, a2 = 0.f, a3 = 0.f;
    float a4 = 0.f, a5 = 0.f, a6 = 0.f, a7 = 0.f;
    for (; p + 7 < end; p += 8) {
        int s0 = esrc[p],     s1 = esrc[p + 1], s2 = esrc[p + 2], s3 = esrc[p + 3];
        int s4 = esrc[p + 4], s5 = esrc[p + 5], s6 = esrc[p + 6], s7 = esrc[p + 7];
        a0 += bf2f(feat[(size_t)s0 * 16 + j]);
        a1 += bf2f(feat[(size_t)s1 * 16 + j]);
        a2 += bf2f(feat[(size_t)s2 * 16 + j]);
        a3 += bf2f(feat[(size_t)s3 * 16 + j]);
        a4 += bf2f(feat[(size_t)s4 * 16 + j]);
        a5 += bf2f(feat[(size_t)s5 * 16 + j]);
        a6 += bf2f(feat[(size_t)s6 * 16 + j]);
        a7 += bf2f(feat[(size_t)s7 * 16 + j]);
    }
    for (; p < end; ++p) a0 += bf2f(feat[(size_t)esrc[p] * 16 + j]);
    float acc = ((a0 + a1) + (a2 + a3)) + ((a4 + a5) + (a6 + a7));
    float ns = rsqrtf((float)max(cntS[d], 1));
    float v = fmaxf(acc * norm_dst[d] + b1[j], 0.f) * ns;
    h1s[(size_t)d * 16 + j] = f2bf(v);
}

// ---------------------------------------------------------------------------
// Aggregate layer 2 (CSR, 8-deep) + fused final GEMM:
//   out[d][:] = (sum @ W2) * nd + b2
// ---------------------------------------------------------------------------
__global__ __launch_bounds__(NT) void aggregate_final(const unsigned short* __restrict__ feat,
                                                      const int* __restrict__ rowoff,
                                                      const int* __restrict__ rowend,
                                                      const int* __restrict__ esrc,
                                                      const float* __restrict__ norm_dst,
                                                      const float* __restrict__ W2,
                                                      const float* __restrict__ b2,
                                                      float* __restrict__ out, int n) {
    __shared__ float sW[16 * 64];
    int tid = threadIdx.x;
    *(float4*)&sW[tid * 4] = *(const float4*)&W2[tid * 4];
    __syncthreads();
    int d = blockIdx.x * 16 + (tid >> 4);
    int j = tid & 15;
    if (d >= n) return;
    int p = rowoff[d], end = rowend[d];
    float a0 = 0.f, a1 = 0.f, a2 = 0.f, a3 = 0.f;
    float a4 = 0.f, a5 = 0.f, a6 = 0.f, a7 = 0.f;
    for (; p + 7 < end; p += 8) {
        int s0 = esrc[p],     s1 = esrc[p + 1], s2 = esrc[p + 2], s3 = esrc[p + 3];
        int s4 = esrc[p + 4], s5 = esrc[p + 5], s6 = esrc[p + 6], s7 = esrc[p + 7];
        a0 += bf2f(feat[(size_t)s0 * 16 + j]);
        a1 += bf2f(feat[(size_t)s1 * 16 + j]);
        a2 += bf2f(feat[(size_t)s2 * 16 + j]);
        a3 += bf2f(feat[(size_t)s3 * 16 + j]);
        a4 += bf2f(feat[(size_t)s4 * 16 + j]);
        a5 += bf2f(feat[(size_t)s5 * 16 + j]);
        a6 += bf2f(feat[(size_t)s6 * 16 + j]);
        a7 += bf2f(feat[(size_t)s7 * 16 + j]);
    }
    for (; p < end; ++p) a0 += bf2f(feat[(size_t)esrc[p] * 16 + j]);
    float acc = ((a0 + a1) + (a2 + a3)) + ((a4 + a5) + (a6 + a7));
    float nd = norm_dst[d];
    float o0 = 0.f, o1 = 0.f, o2 = 0.f, o3 = 0.f;
#pragma unroll
    for (int k = 0; k < 16; k++) {
        float ak = __shfl(acc, k, 16);
        o0 += ak * sW[k * 64 + j];
        o1 += ak * sW[k * 64 + j + 16];
        o2 += ak * sW[k * 64 + j + 32];
        o3 += ak * sW[k * 64 + j + 48];
    }
    size_t ob = (size_t)d * 64;
    out[ob + j]      = o0 * nd + b2[j];
    out[ob + j + 16] = o1 * nd + b2[j + 16];
    out[ob + j + 32] = o2 * nd + b2[j + 32];
    out[ob + j + 48] = o3 * nd + b2[j + 48];
}

// ---------------------------------------------------------------------------
// Launch
// ---------------------------------------------------------------------------
extern "C" void kernel_launch(void* const* d_in, const int* in_sizes, int n_in,
                              void* d_out, int out_size, void* d_ws, size_t ws_size,
                              hipStream_t stream) {
    const float* x  = (const float*)d_in[0];
    const float* W1 = (const float*)d_in[1];
    const float* b1 = (const float*)d_in[2];
    const float* W2 = (const float*)d_in[3];
    const float* b2 = (const float*)d_in[4];
    const int* src  = (const int*)d_in[5];
    const int* dst  = (const int*)d_in[6];

    int n = in_sizes[0] / 512;   // 100000
    int e = in_sizes[5];         // 3200000
    float* out = (float*)d_out;

    int nbf = (n + 255) >> 8;    // 391 fine buckets

    char* ws = (char*)d_ws;
    size_t off = 0;
    auto alloc = [&](size_t bytes) { size_t o = off; off = (off + bytes + 255) & ~(size_t)255; return o; };
    int*   cntS   = (int*)(ws + alloc((size_t)n * 4));   // zeroed by memset
    size_t zero_end = off;
    int*   gcurCD = (int*)(ws + alloc(NBC * 4));
    int*   gcurCS = (int*)(ws + alloc(NBC * 4));
    int*   gcurF  = (int*)(ws + alloc(MAXF * 4));
    float* norm_dst = (float*)(ws + alloc((size_t)n * 4));
    int*   rowoff   = (int*)(ws + alloc((size_t)n * 4));
    int*   rowend   = (int*)(ws + alloc((size_t)n * 4));
    unsigned int*   ebinCD = (unsigned int*)(ws + alloc((size_t)NBC * CAPC * 4));
    unsigned short* ebinCS = (unsigned short*)(ws + alloc((size_t)NBC * CAPC * 2));
    unsigned int*   ebinD  = (unsigned int*)(ws + alloc((size_t)nbf * CAP * 4));
    int*   esrc  = (int*)(ws + alloc((size_t)nbf * CAP * 4));
    unsigned short* y1bf = (unsigned short*)(ws + alloc((size_t)n * 16 * 2));
    unsigned short* h1s  = (unsigned short*)(ws + alloc((size_t)n * 16 * 2));
    unsigned short* w1t_hi = (unsigned short*)(ws + alloc(16 * 512 * 2));
    unsigned short* w1t_lo = (unsigned short*)(ws + alloc(16 * 512 * 2));
    if (off > ws_size) return;

    int cbb = (e + EPBC - 1) / EPBC;      // 391
    int fsb = NBC * 16;                   // 784 (fine + s_hist halves)
    int grb = (n + GR - 1) / GR;          // 1563
    int agb = (n + 15) / 16;              // 6250

    hipMemsetAsync(cntS, 0, zero_end, stream);

    init_all       <<<17, 512, 0, stream>>>(gcurCD, gcurCS, gcurF, W1, w1t_hi, w1t_lo, nbf);
    coarse_scatter <<<cbb, NT, 0, stream>>>(src, dst, gcurCD, gcurCS, ebinCD, ebinCS, e);
    fine_plus_shist<<<fsb, NT, 0, stream>>>(ebinCD, gcurCD, gcurF, ebinD, ebinCS, gcurCS, cntS, n);
    gemm1_mfma     <<<grb, NT, 0, stream>>>(x, w1t_hi, w1t_lo, cntS, y1bf, n);
    dst_fill       <<<nbf, NT, 0, stream>>>(ebinD, gcurF, rowoff, rowend, norm_dst, esrc, n);
    aggregate_act  <<<agb, NT, 0, stream>>>(y1bf, rowoff, rowend, esrc, norm_dst, cntS, b1, h1s, n);
    aggregate_final<<<agb, NT, 0, stream>>>(h1s, rowoff, rowend, esrc, norm_dst, W2, b2, out, n);
}